// Round 13
// baseline (167.242 us; speedup 1.0000x reference)
//
#include <hip/hip_runtime.h>

typedef __bf16 bf16_t;
typedef __bf16 bf16x8 __attribute__((ext_vector_type(8)));
typedef float f32x4 __attribute__((ext_vector_type(4)));
typedef unsigned long long u64;

__device__ __forceinline__ unsigned short bfbits(float f) {
  unsigned u = __float_as_uint(f);
  u += 0x7fffu + ((u >> 16) & 1u);           // RNE
  return (unsigned short)(u >> 16);
}
__device__ __forceinline__ bf16_t f2bf(float f) {
  unsigned short s = bfbits(f);
  union { unsigned short s; bf16_t b; } cv; cv.s = s; return cv.b;
}

__device__ __forceinline__ void gl16(const void* g, void* l) {
  __builtin_amdgcn_global_load_lds(
      (const __attribute__((address_space(1))) void*)g,
      (__attribute__((address_space(3))) void*)l,
      16, 0, 0);
}

// ---- fused fp32 -> bf16 convert for x and W, k-chunk swizzled for GEMM ----
__global__ __launch_bounds__(256) void cvt_kernel(const float* __restrict__ x,
                                                  const float* __restrict__ Wf,
                                                  bf16_t* __restrict__ xb,
                                                  bf16_t* __restrict__ wb) {
  const int i = blockIdx.x * 256 + threadIdx.x;
  const float* src; bf16_t* dst; int j;
  if (i < 524288) { j = i; src = x; dst = xb; }
  else            { j = i - 524288; src = Wf; dst = wb; }
  const float4* s = (const float4*)src + (size_t)j * 2;
  float4 a = s[0], b = s[1];
  bf16x8 o;
  o[0] = f2bf(a.x); o[1] = f2bf(a.y); o[2] = f2bf(a.z); o[3] = f2bf(a.w);
  o[4] = f2bf(b.x); o[5] = f2bf(b.y); o[6] = f2bf(b.z); o[7] = f2bf(b.w);
  const int row = j >> 7, jr = j & 127;
  const int dstc = (row << 7) + (jr & ~3) + ((jr & 3) ^ ((row >> 1) & 3));
  *((bf16x8*)dst + dstc) = o;
}

// ---------------- QKV GEMM: C[m,n] = sum_k A[m,k]*W[n,k] + bias[n] ------
// Depth-2 global_load_lds pipeline, FULLY UNROLLED steady state: all 30
// phases straight-line, slots compile-time (t%3), vmcnt(4) + one barrier
// per phase. Schedule shape is pinned independent of co-compile regalloc.
#define GEMM_K 1024
__global__ __launch_bounds__(256) void qkv_gemm(
    const bf16_t* __restrict__ A,   // [4096][1024] bf16, k-chunk swizzled
    const bf16_t* __restrict__ B,   // [3072][1024] bf16, k-chunk swizzled
    const float* __restrict__ bias, // [3072]
    float* __restrict__ Ko, float* __restrict__ Vo,          // d_out (plain)
    bf16_t* __restrict__ Qb, bf16_t* __restrict__ Kb,        // ws, tile-swizzled
    bf16_t* __restrict__ Vt,                                 // ws, tile-swizzled [hd][key]
    int* __restrict__ qcnt)                                  // attn task queue
{
  if (blockIdx.x == 0 && threadIdx.x == 0) *qcnt = 0;
  __shared__ bf16_t lsA[3][4096];   // 3 x 8 KB (128x32 bf16 tiles)
  __shared__ bf16_t lsB[3][4096];
  const int tid = threadIdx.x;
  const int lane = tid & 63;
  const int ln = lane & 15, qd = lane >> 4;
  const int wid = tid >> 6;
  const int wm = wid & 1, wn = wid >> 1;
  // XCD-aware remap: blocks on one XCD share a 3-tile B slice (768 KB, L2-fits)
  const int xcd = blockIdx.x & 7;
  const int j = blockIdx.x >> 3;          // 0..95
  const int bn = xcd * 3 + (j % 3);       // 0..23
  const int bm = j / 3;                   // 0..31
  const int m0 = bm * 128, n0 = bn * 128;
  const int qs = qd ^ ((ln >> 1) & 3);

  f32x4 acc[4][4] = {};

  const int c0 = tid, c1 = tid + 256;
  const bf16_t* ga0 = A + (size_t)(m0 + (c0 >> 2)) * GEMM_K + (c0 & 3) * 8;
  const bf16_t* ga1 = A + (size_t)(m0 + (c1 >> 2)) * GEMM_K + (c1 & 3) * 8;
  const bf16_t* gb0 = B + (size_t)(n0 + (c0 >> 2)) * GEMM_K + (c0 & 3) * 8;
  const bf16_t* gb1 = B + (size_t)(n0 + (c1 >> 2)) * GEMM_K + (c1 & 3) * 8;

#define STAGE(t, slot)                                   \
  do {                                                   \
    const int ko_ = (t) * 32;                            \
    gl16(ga0 + ko_, &lsA[(slot)][c0 * 8]);               \
    gl16(ga1 + ko_, &lsA[(slot)][c1 * 8]);               \
    gl16(gb0 + ko_, &lsB[(slot)][c0 * 8]);               \
    gl16(gb1 + ko_, &lsB[(slot)][c1 * 8]);               \
  } while (0)

#define COMPUTE(slot)                                                          \
  do {                                                                         \
    bf16x8 af[4], bf[4];                                                       \
    _Pragma("unroll")                                                          \
    for (int mi = 0; mi < 4; ++mi)                                             \
      af[mi] = *(const bf16x8*)&lsA[(slot)][(wm * 64 + mi * 16 + ln) * 32 + qs * 8]; \
    _Pragma("unroll")                                                          \
    for (int ni = 0; ni < 4; ++ni)                                             \
      bf[ni] = *(const bf16x8*)&lsB[(slot)][(wn * 64 + ni * 16 + ln) * 32 + qs * 8]; \
    _Pragma("unroll")                                                          \
    for (int mi = 0; mi < 4; ++mi)                                             \
      _Pragma("unroll")                                                        \
      for (int ni = 0; ni < 4; ++ni)                                           \
        acc[mi][ni] = __builtin_amdgcn_mfma_f32_16x16x32_bf16(af[mi], bf[ni], acc[mi][ni], 0, 0, 0); \
  } while (0)

#define WAITBAR(n)                                        \
  do {                                                    \
    asm volatile("s_waitcnt vmcnt(" #n ")" ::: "memory"); \
    __builtin_amdgcn_s_barrier();                         \
  } while (0)

  // prologue: tiles 0 (slot 0) and 1 (slot 1) in flight
  STAGE(0, 0);
  STAGE(1, 1);
  // steady state, fully unrolled: tile t -> slot t%3; vmcnt(4) leaves tile
  // t+1's 4 loads in flight across the barrier; stage tile t+2; compute t.
#pragma unroll
  for (int t = 0; t < 30; ++t) {
    WAITBAR(4);
    STAGE(t + 2, (t + 2) % 3);
    COMPUTE(t % 3);
  }
  // epilogue: tiles 30 (slot 0) and 31 (slot 1)
  WAITBAR(4); COMPUTE(0);
  WAITBAR(0); COMPUTE(1);

#undef STAGE
#undef COMPUTE
#undef WAITBAR

  const int sec = n0 >> 10;
#pragma unroll
  for (int mi = 0; mi < 4; ++mi) {
#pragma unroll
    for (int ni = 0; ni < 4; ++ni) {
      const int colg = n0 + wn * 64 + ni * 16 + ln;
      const float bv = bias[colg];
      const int cc = colg & 1023, h = cc >> 6, hd = cc & 63;
      if (sec == 2) {
        // V: fp32 to d_out + u64-packed bf16 transpose (4 s-consecutive vals)
        unsigned u[4];
#pragma unroll
        for (int r = 0; r < 4; ++r) {
          const int mg = m0 + wm * 64 + mi * 16 + qd * 4 + r;
          const int b = mg >> 11, s = mg & 2047;
          const float val = acc[mi][ni][r] + bv;
          Vo[((size_t)((b * 16 + h) * 2048 + s)) * 64 + hd] = val;
          u[r] = __float_as_uint(val);
        }
        const int mg0 = m0 + wm * 64 + mi * 16 + qd * 4;
        const int b0 = mg0 >> 11, s0 = mg0 & 2047;
        const unsigned lo = (u[1] & 0xFFFF0000u) | (u[0] >> 16);
        const unsigned hi = (u[3] & 0xFFFF0000u) | (u[2] >> 16);
        const size_t vb = (size_t)(b0 * 16 + h) * 131072 + (size_t)(s0 >> 6) * 4096 +
                          (size_t)hd * 64 + ((((s0 >> 3) & 7) ^ (hd & 7)) << 3) + (s0 & 7);
        *(u64*)&Vt[vb] = ((u64)hi << 32) | lo;
      } else {
#pragma unroll
        for (int r = 0; r < 4; ++r) {
          const int mg = m0 + wm * 64 + mi * 16 + qd * 4 + r;
          const int b = mg >> 11, s = mg & 2047;
          const float val = acc[mi][ni][r] + bv;
          const int bhi = b * 16 + h;
          const size_t sidx = (size_t)bhi * 131072 + (size_t)(s >> 6) * 4096 +
                              (size_t)(s & 63) * 64 + (((hd >> 3) ^ (s & 7)) << 3) + (hd & 7);
          if (sec == 0) {
            Qb[sidx] = f2bf(val * 0.18033688f);  // fold 1/sqrt(64) * log2(e)
          } else {
            Ko[((size_t)(bhi * 2048 + s)) * 64 + hd] = val;
            Kb[sidx] = f2bf(val);
          }
        }
      }
    }
  }
}

// -------- Flash attention: 64-key tiles, key-axis split for load balance ----
// 768 tasks on 512 blocks, all tasks <= 8 supertile-units (old max was 16):
//  tasks   0..255: Heavy-A  (bh, it=8..15), key-tiles 0..15, partial -> Out rows (raw) + LA
//  tasks 256..767: LPT mix of Heavy-B (it=15..8, key-tiles 16..2it+1, diag) -> PB + LB
//                  and Light (it=7..0, full range) -> Out (normalized)
// No-max softmax (p = exp2(s)) makes partials ADDITIVE: combine_kernel does
// Out = (OutA + PB) / (LA + LB) for the heavy rows. Separate buffers -> no
// atomics, no races. Compute body identical to R12 (static-slot dbuf).
__global__ __launch_bounds__(512, 4) void attn_kernel(
    const bf16_t* __restrict__ Qb,  // tile-swizzled, pre-scaled by 0.125*log2e
    const bf16_t* __restrict__ Kb,
    const bf16_t* __restrict__ Vt,  // tile-swizzled [hd][key]
    float* __restrict__ Out,        // [b,s,1024]
    float* __restrict__ PB,         // 8 MB partial O (heavy-B), compact layout
    float* __restrict__ LA,         // 128 KB partial lsum (heavy-A)
    float* __restrict__ LB,         // 128 KB partial lsum (heavy-B)
    int* __restrict__ qcnt)
{
  __shared__ bf16_t lk[2][4096];  // 2 x 8 KB (64-key tiles)
  __shared__ bf16_t lv[2][4096];  // 2 x 8 KB
  __shared__ bf16_t lp[8192];     // 16 KB (P rows, wave-private 16-row stripes)
  __shared__ int task_sh;
  const int tid = threadIdx.x;
  const int lane = tid & 63, ln = lane & 15, qd = lane >> 4;
  const int w = tid >> 6;       // 0..7
  const int l7 = ln & 7;

  for (;;) {
    __syncthreads();
    if (tid == 0) task_sh = atomicAdd(qcnt, 1);
    __syncthreads();
    const int task = task_sh;
    if (task >= 768) break;
    int bh, it, kt0, ktN, mode;    // mode: 0=light full, 1=heavy-A, 2=heavy-B
    if (task < 256) {              // Heavy-A: size 8, popped first (LPT)
      bh = task & 31; it = 8 + ((task >> 5) & 7);
      kt0 = 0; ktN = 16; mode = 1;
    } else {                       // descending-size mix of Heavy-B and Light
      const int p = task - 256, grp = p >> 6, within = p & 63;
      if (within < 32) { bh = within;      it = 15 - grp; kt0 = 16; ktN = 2 * (it + 1) - 16; mode = 2; }
      else             { bh = within - 32; it = 7 - grp;  kt0 = 0;  ktN = 2 * (it + 1);      mode = 0; }
    }
    const int b = bh >> 4, h = bh & 15;

    const bf16_t* qbase = Qb + (size_t)bh * 131072 + (size_t)it * 8192;
    const bf16_t* kbase = Kb + (size_t)bh * 131072;
    const bf16_t* vbase = Vt + (size_t)bh * 131072;

    f32x4 oc[4] = {};
    float lsum = 0.f;
    const int qg = it * 128 + w * 16 + ln;
    const int q = w * 16 + ln;

#define STG(t, slot)                                              \
    do {                                                          \
      gl16(kbase + (size_t)(t) * 4096 + tid * 8, &lk[(slot)][tid * 8]); \
      gl16(vbase + (size_t)(t) * 4096 + tid * 8, &lv[(slot)][tid * 8]); \
    } while (0)

#define CTILE(kt, slot)                                                        \
    do {                                                                       \
      if (!((kt) == 2 * it + 1 && w < 4)) {                                    \
        const bool diag = ((kt) >= 2 * it);                                    \
        f32x4 sa[4] = {};                                                      \
        _Pragma("unroll")                                                      \
        for (int kk = 0; kk < 2; ++kk) {                                       \
          bf16x8 ak[4];                                                        \
          _Pragma("unroll")                                                    \
          for (int ki = 0; ki < 4; ++ki)                                       \
            ak[ki] = *(const bf16x8*)&lk[(slot)][(ki * 16 + ln) * 64 + (((kk * 4 + qd) ^ l7) << 3)]; \
          _Pragma("unroll")                                                    \
          for (int ki = 0; ki < 4; ++ki)                                       \
            sa[ki] = __builtin_amdgcn_mfma_f32_16x16x32_bf16(ak[ki], afq[kk], sa[ki], 0, 0, 0); \
        }                                                                      \
        _Pragma("unroll")                                                      \
        for (int ki = 0; ki < 4; ++ki) {                                       \
          const int kb0 = (kt) * 64 + ki * 16 + qd * 4;                        \
          float p0 = __builtin_amdgcn_exp2f(sa[ki][0]);                        \
          float p1 = __builtin_amdgcn_exp2f(sa[ki][1]);                        \
          float p2 = __builtin_amdgcn_exp2f(sa[ki][2]);                        \
          float p3 = __builtin_amdgcn_exp2f(sa[ki][3]);                        \
          if (diag) {                                                          \
            if (kb0 + 0 > qg) p0 = 0.f;                                        \
            if (kb0 + 1 > qg) p1 = 0.f;                                        \
            if (kb0 + 2 > qg) p2 = 0.f;                                        \
            if (kb0 + 3 > qg) p3 = 0.f;                                        \
          }                                                                    \
          lsum += (p0 + p1) + (p2 + p3);                                       \
          const unsigned lo = (__float_as_uint(p1) & 0xFFFF0000u) | (__float_as_uint(p0) >> 16); \
          const unsigned hi = (__float_as_uint(p3) & 0xFFFF0000u) | (__float_as_uint(p2) >> 16); \
          const int g = (ki * 2 + (qd >> 1)) ^ l7;                             \
          *(u64*)&lp[q * 64 + g * 8 + (qd & 1) * 4] = ((u64)hi << 32) | lo;    \
        }                                                                      \
        _Pragma("unroll")                                                      \
        for (int kk = 0; kk < 2; ++kk) {                                       \
          bf16x8 afp, bfv[4];                                                  \
          afp = *(const bf16x8*)&lp[q * 64 + (((kk * 4 + qd) ^ l7) << 3)];     \
          _Pragma("unroll")                                                    \
          for (int ni = 0; ni < 4; ++ni)                                       \
            bfv[ni] = *(const bf16x8*)&lv[(slot)][(ni * 16 + ln) * 64 + (((kk * 4 + qd) ^ l7) << 3)]; \
          _Pragma("unroll")                                                    \
          for (int ni = 0; ni < 4; ++ni)                                       \
            oc[ni] = __builtin_amdgcn_mfma_f32_16x16x32_bf16(afp, bfv[ni], oc[ni], 0, 0, 0); \
        }                                                                      \
      }                                                                        \
    } while (0)

#define WB0                                               \
    do {                                                  \
      asm volatile("s_waitcnt vmcnt(0)" ::: "memory");    \
      __builtin_amdgcn_s_barrier();                       \
    } while (0)

    // prologue: first tile -> slot 0; Q fragments direct global->VGPR
    STG(kt0, 0);
    bf16x8 afq[2];
    {
      const int row = w * 16 + ln;
#pragma unroll
      for (int kk = 0; kk < 2; ++kk)
        afq[kk] = *(const bf16x8*)(qbase + (row >> 6) * 4096 + (row & 63) * 64 +
                                   (((kk * 4 + qd) ^ l7) << 3));
    }
    WB0;

    for (int s = 0; s < ktN; s += 2) {   // ktN always even (2(it+1) or 16 or 2it-14)
      STG(kt0 + s + 1, 1);
      CTILE(kt0 + s, 0);
      WB0;
      if (s + 2 < ktN) STG(kt0 + s + 2, 0);
      CTILE(kt0 + s + 1, 1);
      WB0;
    }

#undef STG
#undef CTILE
#undef WB0

    // epilogue: reduce lsum across quads; store per mode
    float ls = lsum;
    ls += __shfl_xor(ls, 16);
    ls += __shfl_xor(ls, 32);
#pragma unroll
    for (int r = 0; r < 4; ++r) {
      const float lval = __shfl(ls, qd * 4 + r);
      const int rowl = w * 16 + qd * 4 + r;      // 0..127
      const int rowq = it * 128 + rowl;
      if (mode == 0) {
        const float inv = 1.0f / lval;
#pragma unroll
        for (int ni = 0; ni < 4; ++ni)
          Out[(size_t)(b * 2048 + rowq) * 1024 + h * 64 + ni * 16 + ln] = oc[ni][r] * inv;
      } else if (mode == 1) {
        // raw partial to final Out rows (s >= 1024, overwritten by combine)
#pragma unroll
        for (int ni = 0; ni < 4; ++ni)
          Out[(size_t)(b * 2048 + rowq) * 1024 + h * 64 + ni * 16 + ln] = oc[ni][r];
        if (ln == 0) LA[bh * 1024 + (it - 8) * 128 + rowl] = lval;
      } else {
        const int pr = bh * 1024 + (it - 8) * 128 + rowl;
#pragma unroll
        for (int ni = 0; ni < 4; ++ni)
          PB[(size_t)pr * 64 + ni * 16 + ln] = oc[ni][r];
        if (ln == 0) LB[pr] = lval;
      }
    }
  }
}

// -------- combine: heavy rows Out = (OutA + PB) / (LA + LB) -----------------
__global__ __launch_bounds__(256) void combine_kernel(
    float* __restrict__ Out, const float* __restrict__ PB,
    const float* __restrict__ LA, const float* __restrict__ LB) {
  const int e = blockIdx.x * 256 + threadIdx.x;    // 0..2M-1
  const int bhrow = e >> 6, hd = e & 63;
  const int bh = bhrow >> 10, rloc = bhrow & 1023; // rloc = (it-8)*128 + rowl
  const int b = bh >> 4, h = bh & 15;
  const size_t oaddr = ((size_t)(b * 2048 + 1024 + rloc)) * 1024 + h * 64 + hd;
  Out[oaddr] = (Out[oaddr] + PB[e]) / (LA[bhrow] + LB[bhrow]);
}

extern "C" void kernel_launch(void* const* d_in, const int* in_sizes, int n_in,
                              void* d_out, int out_size, void* d_ws, size_t ws_size,
                              hipStream_t stream) {
  const float* x = (const float*)d_in[0];   // [2,2048,1024]
  const float* W = (const float*)d_in[1];   // [3072,1024]
  const float* bq = (const float*)d_in[2];  // [3072]
  float* out = (float*)d_out;               // out | K | V
  float* Ko = out + 4194304;
  float* Vo = out + 8388608;
  char* ws = (char*)d_ws;
  bf16_t* xb = (bf16_t*)ws;                      // 8 MB (reused as PB after gemm)
  bf16_t* wb = (bf16_t*)(ws + 8388608);          // 6 MB (reused as LA/LB after gemm)
  bf16_t* Qb = (bf16_t*)(ws + 14680064);         // 8 MB
  bf16_t* Kb = (bf16_t*)(ws + 23068672);         // 8 MB
  bf16_t* Vt = (bf16_t*)(ws + 31457280);         // 8 MB
  int*    qcnt = (int*)(ws + 39845888);          // 4 B task counter
  float*  PB = (float*)ws;                       // 8 MB partial O (xb region, dead after gemm)
  float*  LA = (float*)(ws + 8388608);           // 128 KB (wb region, dead after gemm)
  float*  LB = (float*)(ws + 8519680);           // 128 KB

  hipLaunchKernelGGL(cvt_kernel, dim3(3584), dim3(256), 0, stream, x, W, xb, wb);
  hipLaunchKernelGGL(qkv_gemm, dim3(768), dim3(256), 0, stream, xb, wb, bq, Ko, Vo, Qb, Kb, Vt, qcnt);
  hipLaunchKernelGGL(attn_kernel, dim3(512), dim3(512), 0, stream, Qb, Kb, Vt, out, PB, LA, LB, qcnt);
  hipLaunchKernelGGL(combine_kernel, dim3(8192), dim3(256), 0, stream, out, PB, LA, LB);
}

// Round 14
// 161.234 us; speedup vs baseline: 1.0373x; 1.0373x over previous
//
#include <hip/hip_runtime.h>

typedef __bf16 bf16_t;
typedef __bf16 bf16x8 __attribute__((ext_vector_type(8)));
typedef float f32x4 __attribute__((ext_vector_type(4)));
typedef unsigned long long u64;

__device__ __forceinline__ unsigned short bfbits(float f) {
  unsigned u = __float_as_uint(f);
  u += 0x7fffu + ((u >> 16) & 1u);           // RNE
  return (unsigned short)(u >> 16);
}
__device__ __forceinline__ bf16_t f2bf(float f) {
  unsigned short s = bfbits(f);
  union { unsigned short s; bf16_t b; } cv; cv.s = s; return cv.b;
}

__device__ __forceinline__ void gl16(const void* g, void* l) {
  __builtin_amdgcn_global_load_lds(
      (const __attribute__((address_space(1))) void*)g,
      (__attribute__((address_space(3))) void*)l,
      16, 0, 0);
}

// ---- fused fp32 -> bf16 convert for x and W, k-chunk swizzled for GEMM ----
__global__ __launch_bounds__(256) void cvt_kernel(const float* __restrict__ x,
                                                  const float* __restrict__ Wf,
                                                  bf16_t* __restrict__ xb,
                                                  bf16_t* __restrict__ wb) {
  const int i = blockIdx.x * 256 + threadIdx.x;
  const float* src; bf16_t* dst; int j;
  if (i < 524288) { j = i; src = x; dst = xb; }
  else            { j = i - 524288; src = Wf; dst = wb; }
  const float4* s = (const float4*)src + (size_t)j * 2;
  float4 a = s[0], b = s[1];
  bf16x8 o;
  o[0] = f2bf(a.x); o[1] = f2bf(a.y); o[2] = f2bf(a.z); o[3] = f2bf(a.w);
  o[4] = f2bf(b.x); o[5] = f2bf(b.y); o[6] = f2bf(b.z); o[7] = f2bf(b.w);
  const int row = j >> 7, jr = j & 127;
  const int dstc = (row << 7) + (jr & ~3) + ((jr & 3) ^ ((row >> 1) & 3));
  *((bf16x8*)dst + dstc) = o;
}

// ---------------- QKV GEMM: C[m,n] = sum_k A[m,k]*W[n,k] + bias[n] ------
// 256x128 tile, 8 waves (4 row x 2 col), 512 threads. Depth-2 global_load_lds
// pipeline, FULLY UNROLLED: 3 static slots (72 KB LDS), 3 gl16/thread/tile,
// counted vmcnt(3). +33% MFMA per staged byte vs 128x128; B traffic halves.
#define GEMM_K 1024
__global__ __launch_bounds__(512, 4) void qkv_gemm(
    const bf16_t* __restrict__ A,   // [4096][1024] bf16, k-chunk swizzled
    const bf16_t* __restrict__ B,   // [3072][1024] bf16, k-chunk swizzled
    const float* __restrict__ bias, // [3072]
    float* __restrict__ Ko, float* __restrict__ Vo,          // d_out (plain)
    bf16_t* __restrict__ Qb, bf16_t* __restrict__ Kb,        // ws, tile-swizzled
    bf16_t* __restrict__ Vt,                                 // ws, tile-swizzled [hd][key]
    int* __restrict__ qcnt)                                  // attn task queue
{
  if (blockIdx.x == 0 && threadIdx.x == 0) *qcnt = 0;
  __shared__ bf16_t lsA[3][8192];   // 3 x 16 KB (256x32 bf16 tiles)
  __shared__ bf16_t lsB[3][4096];   // 3 x  8 KB (128x32 bf16 tiles)
  const int tid = threadIdx.x;
  const int lane = tid & 63;
  const int ln = lane & 15, qd = lane >> 4;
  const int wid = tid >> 6;         // 0..7
  const int wm = wid & 3, wn = wid >> 2;   // 4 row-quads x 2 col-halves
  // XCD-aware remap: blocks on one XCD share a 3-tile B slice (L2-fits)
  const int xcd = blockIdx.x & 7;
  const int j = blockIdx.x >> 3;          // 0..47
  const int bn = xcd * 3 + (j % 3);       // 0..23
  const int bm = j / 3;                   // 0..15
  const int m0 = bm * 256, n0 = bn * 128;
  const int qs = qd ^ ((ln >> 1) & 3);

  f32x4 acc[4][4] = {};

  const int c0 = tid, c1 = tid + 512;
  const bf16_t* ga0 = A + (size_t)(m0 + (c0 >> 2)) * GEMM_K + (c0 & 3) * 8;
  const bf16_t* ga1 = A + (size_t)(m0 + (c1 >> 2)) * GEMM_K + (c1 & 3) * 8;
  const bf16_t* gb0 = B + (size_t)(n0 + (c0 >> 2)) * GEMM_K + (c0 & 3) * 8;

#define STAGE(t, slot)                                   \
  do {                                                   \
    const int ko_ = (t) * 32;                            \
    gl16(ga0 + ko_, &lsA[(slot)][c0 * 8]);               \
    gl16(ga1 + ko_, &lsA[(slot)][c1 * 8]);               \
    gl16(gb0 + ko_, &lsB[(slot)][c0 * 8]);               \
  } while (0)

#define COMPUTE(slot)                                                          \
  do {                                                                         \
    bf16x8 af[4], bf[4];                                                       \
    _Pragma("unroll")                                                          \
    for (int mi = 0; mi < 4; ++mi)                                             \
      af[mi] = *(const bf16x8*)&lsA[(slot)][(wm * 64 + mi * 16 + ln) * 32 + qs * 8]; \
    _Pragma("unroll")                                                          \
    for (int ni = 0; ni < 4; ++ni)                                             \
      bf[ni] = *(const bf16x8*)&lsB[(slot)][(wn * 64 + ni * 16 + ln) * 32 + qs * 8]; \
    _Pragma("unroll")                                                          \
    for (int mi = 0; mi < 4; ++mi)                                             \
      _Pragma("unroll")                                                        \
      for (int ni = 0; ni < 4; ++ni)                                           \
        acc[mi][ni] = __builtin_amdgcn_mfma_f32_16x16x32_bf16(af[mi], bf[ni], acc[mi][ni], 0, 0, 0); \
  } while (0)

#define WAITBAR(n)                                        \
  do {                                                    \
    asm volatile("s_waitcnt vmcnt(" #n ")" ::: "memory"); \
    __builtin_amdgcn_s_barrier();                         \
  } while (0)

  // prologue: tiles 0 (slot 0) and 1 (slot 1) in flight
  STAGE(0, 0);
  STAGE(1, 1);
  // steady state, fully unrolled: tile t -> slot t%3; vmcnt(3) leaves tile
  // t+1's 3 loads in flight across the barrier; stage tile t+2; compute t.
#pragma unroll
  for (int t = 0; t < 30; ++t) {
    WAITBAR(3);
    STAGE(t + 2, (t + 2) % 3);
    COMPUTE(t % 3);
  }
  // epilogue: tiles 30 (slot 0) and 31 (slot 1)
  WAITBAR(3); COMPUTE(0);
  WAITBAR(0); COMPUTE(1);

#undef STAGE
#undef COMPUTE
#undef WAITBAR

  const int sec = n0 >> 10;
#pragma unroll
  for (int mi = 0; mi < 4; ++mi) {
#pragma unroll
    for (int ni = 0; ni < 4; ++ni) {
      const int colg = n0 + wn * 64 + ni * 16 + ln;
      const float bv = bias[colg];
      const int cc = colg & 1023, h = cc >> 6, hd = cc & 63;
      if (sec == 2) {
        // V: fp32 to d_out + u64-packed bf16 transpose (4 s-consecutive vals)
        unsigned u[4];
#pragma unroll
        for (int r = 0; r < 4; ++r) {
          const int mg = m0 + wm * 64 + mi * 16 + qd * 4 + r;
          const int b = mg >> 11, s = mg & 2047;
          const float val = acc[mi][ni][r] + bv;
          Vo[((size_t)((b * 16 + h) * 2048 + s)) * 64 + hd] = val;
          u[r] = __float_as_uint(val);
        }
        const int mg0 = m0 + wm * 64 + mi * 16 + qd * 4;
        const int b0 = mg0 >> 11, s0 = mg0 & 2047;
        const unsigned lo = (u[1] & 0xFFFF0000u) | (u[0] >> 16);
        const unsigned hi = (u[3] & 0xFFFF0000u) | (u[2] >> 16);
        const size_t vb = (size_t)(b0 * 16 + h) * 131072 + (size_t)(s0 >> 6) * 4096 +
                          (size_t)hd * 64 + ((((s0 >> 3) & 7) ^ (hd & 7)) << 3) + (s0 & 7);
        *(u64*)&Vt[vb] = ((u64)hi << 32) | lo;
      } else {
#pragma unroll
        for (int r = 0; r < 4; ++r) {
          const int mg = m0 + wm * 64 + mi * 16 + qd * 4 + r;
          const int b = mg >> 11, s = mg & 2047;
          const float val = acc[mi][ni][r] + bv;
          const int bhi = b * 16 + h;
          const size_t sidx = (size_t)bhi * 131072 + (size_t)(s >> 6) * 4096 +
                              (size_t)(s & 63) * 64 + (((hd >> 3) ^ (s & 7)) << 3) + (hd & 7);
          if (sec == 0) {
            Qb[sidx] = f2bf(val * 0.18033688f);  // fold 1/sqrt(64) * log2(e)
          } else {
            Ko[((size_t)(bhi * 2048 + s)) * 64 + hd] = val;
            Kb[sidx] = f2bf(val);
          }
        }
      }
    }
  }
}

// -------- Flash attention: 128-key super-tiles, 8 waves x 16 q-rows ---------
// R11 (best-measured, 51 us): Q fragments direct from global; gl16 staging;
// 48.5 KB LDS; launch_bounds(512,4) -> VGPR 64, no spills.
__global__ __launch_bounds__(512, 4) void attn_kernel(
    const bf16_t* __restrict__ Qb,  // tile-swizzled, pre-scaled by 0.125*log2e
    const bf16_t* __restrict__ Kb,
    const bf16_t* __restrict__ Vt,  // tile-swizzled [hd][key]
    float* __restrict__ Out,        // [b,s,1024]
    int* __restrict__ qcnt)
{
  __shared__ bf16_t lk[8192];   // 16 KB (two 64-key tiles)
  __shared__ bf16_t lv[8192];   // 16 KB
  __shared__ bf16_t lp[8192];   // 16 KB (P rows, wave-private 16-row stripes)
  __shared__ int task_sh;
  const int tid = threadIdx.x;
  const int lane = tid & 63, ln = lane & 15, qd = lane >> 4;
  const int w = tid >> 6;       // 0..7
  const int l7 = ln & 7;

  for (;;) {
    __syncthreads();
    if (tid == 0) task_sh = atomicAdd(qcnt, 1);
    __syncthreads();
    const int task = task_sh;
    if (task >= 512) break;
    // balanced pairing: first 256 pops heavy (it=15..8), next 256 light (0..7)
    const int it = (task < 256) ? (15 - (task >> 5)) : ((task - 256) >> 5);
    const int bh = task & 31;
    const int b = bh >> 4, h = bh & 15;

    const bf16_t* qbase = Qb + (size_t)bh * 131072 + (size_t)it * 8192;
    const bf16_t* kbase = Kb + (size_t)bh * 131072;
    const bf16_t* vbase = Vt + (size_t)bh * 131072;

    // stage K/V super-tile 0 (32 KB over 512 threads)
#pragma unroll
    for (int i = 0; i < 2; ++i) {
      const int cc = tid + i * 512;
      gl16(kbase + cc * 8, &lk[cc * 8]);
      gl16(vbase + cc * 8, &lv[cc * 8]);
    }

    // Q fragments: direct global->VGPR (layout matches old lq[x] = qbase[x])
    bf16x8 afq[2];
    {
      const int row = w * 16 + ln;
#pragma unroll
      for (int kk = 0; kk < 2; ++kk)
        afq[kk] = *(const bf16x8*)(qbase + (row >> 6) * 4096 + (row & 63) * 64 +
                                   (((kk * 4 + qd) ^ l7) << 3));
    }
    __syncthreads();

    f32x4 oc[4] = {};
    float lsum = 0.f;
    const int qg = it * 128 + w * 16 + ln;
    const int q = w * 16 + ln;

    for (int st = 0; st <= it; ++st) {
      if (st > 0) {
        __syncthreads();   // all waves done with prev lk/lv
#pragma unroll
        for (int i = 0; i < 2; ++i) {
          const int cc = tid + i * 512;
          gl16(kbase + (size_t)st * 8192 + cc * 8, &lk[cc * 8]);
          gl16(vbase + (size_t)st * 8192 + cc * 8, &lv[cc * 8]);
        }
        __syncthreads();   // drain stage
      }
      const bool diag = (st == it);

#pragma unroll
      for (int h2 = 0; h2 < 2; ++h2) {
        const int lofs = h2 * 4096;
        // S^T = K * Q^T (rows = keys via quad dim, cols = queries via lane dim)
        f32x4 sa[4] = {};
#pragma unroll
        for (int kk = 0; kk < 2; ++kk) {
          bf16x8 ak[4];
#pragma unroll
          for (int ki = 0; ki < 4; ++ki)
            ak[ki] = *(const bf16x8*)&lk[lofs + (ki * 16 + ln) * 64 + (((kk * 4 + qd) ^ l7) << 3)];
#pragma unroll
          for (int ki = 0; ki < 4; ++ki)
            sa[ki] = __builtin_amdgcn_mfma_f32_16x16x32_bf16(ak[ki], afq[kk], sa[ki], 0, 0, 0);
        }

        // softmax: p = exp2(s) (scale pre-folded into Q); truncation-pack bf16
#pragma unroll
        for (int ki = 0; ki < 4; ++ki) {
          const int kb0 = (st * 2 + h2) * 64 + ki * 16 + qd * 4;
          float p0 = __builtin_amdgcn_exp2f(sa[ki][0]);
          float p1 = __builtin_amdgcn_exp2f(sa[ki][1]);
          float p2 = __builtin_amdgcn_exp2f(sa[ki][2]);
          float p3 = __builtin_amdgcn_exp2f(sa[ki][3]);
          if (diag) {
            if (kb0 + 0 > qg) p0 = 0.f;
            if (kb0 + 1 > qg) p1 = 0.f;
            if (kb0 + 2 > qg) p2 = 0.f;
            if (kb0 + 3 > qg) p3 = 0.f;
          }
          lsum += (p0 + p1) + (p2 + p3);
          const unsigned lo = (__float_as_uint(p1) & 0xFFFF0000u) | (__float_as_uint(p0) >> 16);
          const unsigned hi = (__float_as_uint(p3) & 0xFFFF0000u) | (__float_as_uint(p2) >> 16);
          const int g = (ki * 2 + (qd >> 1)) ^ l7;
          *(u64*)&lp[q * 64 + g * 8 + (qd & 1) * 4] = ((u64)hi << 32) | lo;
        }

        // O += P V   (lp wave-private rows; same-wave order via lgkmcnt)
#pragma unroll
        for (int kk = 0; kk < 2; ++kk) {
          bf16x8 afp, bfv[4];
          afp = *(const bf16x8*)&lp[q * 64 + (((kk * 4 + qd) ^ l7) << 3)];
#pragma unroll
          for (int ni = 0; ni < 4; ++ni)
            bfv[ni] = *(const bf16x8*)&lv[lofs + (ni * 16 + ln) * 64 + (((kk * 4 + qd) ^ l7) << 3)];
#pragma unroll
          for (int ni = 0; ni < 4; ++ni)
            oc[ni] = __builtin_amdgcn_mfma_f32_16x16x32_bf16(afp, bfv[ni], oc[ni], 0, 0, 0);
        }
      }
    }

    // epilogue: reduce lsum across quads, redistribute, normalize, store
    float ls = lsum;
    ls += __shfl_xor(ls, 16);
    ls += __shfl_xor(ls, 32);
#pragma unroll
    for (int r = 0; r < 4; ++r) {
      const float lval = __shfl(ls, qd * 4 + r);
      const float inv = 1.0f / lval;
      const int rowq = it * 128 + w * 16 + qd * 4 + r;
#pragma unroll
      for (int ni = 0; ni < 4; ++ni) {
        const int colh = ni * 16 + ln;
        Out[(size_t)(b * 2048 + rowq) * 1024 + h * 64 + colh] = oc[ni][r] * inv;
      }
    }
  }
}

extern "C" void kernel_launch(void* const* d_in, const int* in_sizes, int n_in,
                              void* d_out, int out_size, void* d_ws, size_t ws_size,
                              hipStream_t stream) {
  const float* x = (const float*)d_in[0];   // [2,2048,1024]
  const float* W = (const float*)d_in[1];   // [3072,1024]
  const float* bq = (const float*)d_in[2];  // [3072]
  float* out = (float*)d_out;               // out | K | V
  float* Ko = out + 4194304;
  float* Vo = out + 8388608;
  char* ws = (char*)d_ws;
  bf16_t* xb = (bf16_t*)ws;                      // 8 MB
  bf16_t* wb = (bf16_t*)(ws + 8388608);          // 6 MB
  bf16_t* Qb = (bf16_t*)(ws + 14680064);         // 8 MB
  bf16_t* Kb = (bf16_t*)(ws + 23068672);         // 8 MB
  bf16_t* Vt = (bf16_t*)(ws + 31457280);         // 8 MB
  int*    qcnt = (int*)(ws + 39845888);          // 4 B task counter

  hipLaunchKernelGGL(cvt_kernel, dim3(3584), dim3(256), 0, stream, x, W, xb, wb);
  hipLaunchKernelGGL(qkv_gemm, dim3(384), dim3(512), 0, stream, xb, wb, bq, Ko, Vo, Qb, Kb, Vt, qcnt);
  hipLaunchKernelGGL(attn_kernel, dim3(512), dim3(512), 0, stream, Qb, Kb, Vt, out, qcnt);
}